// Round 17
// baseline (39.943 us; speedup 1.0000x reference)
//
#include <hip/hip_runtime.h>

typedef __attribute__((ext_vector_type(8))) __bf16 bf16x8;
typedef __attribute__((ext_vector_type(4))) float f32x4;
typedef __attribute__((ext_vector_type(4))) float float4v;
typedef __attribute__((ext_vector_type(4))) unsigned int u32x4;
typedef __attribute__((ext_vector_type(4))) int i32x4;

__device__ __forceinline__ unsigned short f2bfc(float f) {
    __bf16 h = (__bf16)f;
    return __builtin_bit_cast(unsigned short, h);
}

// swizzle on ushort index: XOR bits 3..5 with (row&7)
#define SWZ(idx, row) ((idx) ^ (((row) & 7) << 3))

// barrier flushing LDS ops only; global loads stay in flight
__device__ __forceinline__ void bar_lds() {
    asm volatile("s_waitcnt lgkmcnt(0)" ::: "memory");
    __builtin_amdgcn_s_barrier();
    asm volatile("" ::: "memory");
}

// ---------------------------------------------------------------------------
// kprep v4 (verified r9-r15, reverted to pure form): coalesced LDS-transpose
// -> chunk-major frag image. chunk i = ws[i*16384..+16384) ushorts, i=0..19.
// frag (1KB): lane l = col cb*16+(l&15), k ks*32+(l>>4)*8..+7 of W^T.
// ---------------------------------------------------------------------------
__global__ __launch_bounds__(256) void kprep(
    const float* __restrict__ W1, const float* __restrict__ W2,
    const float* __restrict__ W3, const float* __restrict__ W4,
    unsigned short* __restrict__ ws) {
    __shared__ unsigned short tile[32][33];
    int b = blockIdx.x, t = threadIdx.x;
    const float* W; int ld, tk, tn, wsel;
    if (b < 64)        { W = W1; ld = 512; tk = b >> 4;          tn = b & 15;         wsel = 0; }
    else if (b < 128)  { W = W2; ld = 128; tk = (b - 64) >> 2;   tn = (b - 64) & 3;   wsel = 1; }
    else if (b < 256)  { W = W3; ld = 512; tk = (b - 128) >> 4;  tn = (b - 128) & 15; wsel = 2; }
    else               { W = W4; ld = 128; tk = (b - 256) >> 2;  tn = (b - 256) & 3;  wsel = 3; }
#pragma unroll
    for (int it = 0; it < 4; it++) {
        int e = t + it * 256;
        int kr = e >> 5, nc = e & 31;
        tile[kr][nc] = f2bfc(W[(tk * 32 + kr) * ld + tn * 32 + nc]);
    }
    __syncthreads();
    int ks = tk;
#pragma unroll
    for (int it = 0; it < 2; it++) {
        int u2  = (t + it * 256) * 2;
        int cbl = u2 >> 9;
        int w   = u2 & 511;
        int lane = w >> 3, e0 = w & 7;
        int c  = lane & 15;
        int kk = (lane >> 4) * 8 + e0;
        unsigned int lo = tile[kk][cbl * 16 + c];
        unsigned int hi = tile[kk + 1][cbl * 16 + c];
        int cb = tn * 2 + cbl;
        int fi;
        if (wsel == 0)      fi = (cb >> 3) * 32 + (cb & 7) * 4 + ks;
        else if (wsel == 1) fi = 128 + (ks >> 2) * 32 + cb * 4 + (ks & 3);
        else if (wsel == 2) fi = 256 + ((cb >> 3) * 2 + (ks >> 2)) * 32 + (cb & 7) * 4 + (ks & 3);
        else                fi = 512 + (ks >> 2) * 32 + cb * 4 + (ks & 3);
        ((unsigned int*)ws)[fi * 256 + (w >> 1)] = lo | (hi << 16);
    }
}

// load one chunk's 8 frags for this wave's wn (32 cols x 128 k)
__device__ __forceinline__ void ldch8(const unsigned short* __restrict__ wsw, int i,
                                      bf16x8 (&B)[8]) {
#pragma unroll
    for (int n = 0; n < 2; n++)
#pragma unroll
        for (int ks = 0; ks < 4; ks++)
            B[ks * 2 + n] = *(const bf16x8*)(wsw + i * 16384 + n * 2048 + ks * 512);
}

// A from LDS (wave's 16 rows), B regs; acc[2] = 16 rows x 32 cols
__device__ __forceinline__ void mmA_lds(const unsigned short* __restrict__ A,
                                        int astride, int akoff, const bf16x8 (&b)[8],
                                        int rowa, int lk, f32x4 (&acc)[2]) {
#pragma unroll
    for (int ks = 0; ks < 4; ks++) {
        bf16x8 a = *(const bf16x8*)(&A[SWZ(rowa * astride + akoff + ks * 32 + lk, rowa)]);
#pragma unroll
        for (int n = 0; n < 2; n++)
            acc[n] = __builtin_amdgcn_mfma_f32_16x16x32_bf16(a, b[ks * 2 + n], acc[n], 0, 0, 0);
    }
}

__device__ __forceinline__ void mmRegA(const bf16x8 (&a1f)[4], const bf16x8 (&b)[8],
                                       f32x4 (&acc)[2]) {
#pragma unroll
    for (int ks = 0; ks < 4; ks++)
#pragma unroll
        for (int n = 0; n < 2; n++)
            acc[n] = __builtin_amdgcn_mfma_f32_16x16x32_bf16(a1f[ks], b[ks * 2 + n], acc[n], 0, 0, 0);
}

template<bool RELU>
__device__ __forceinline__ void epi_store(unsigned short* dst, int dstride, int colbase,
                                          const f32x4 (&acc)[2], const float (&bias)[2],
                                          int lr, int lq, int row0, int wn) {
#pragma unroll
    for (int n = 0; n < 2; n++) {
        int col = colbase + wn * 32 + n * 16 + lr;
#pragma unroll
        for (int r = 0; r < 4; r++) {
            int row = row0 + lq + r;
            float v = acc[n][r] + bias[n];
            if (RELU) v = fmaxf(v, 0.0f);
            dst[SWZ(row * dstride + col, row)] = f2bfc(v);
        }
    }
}

#define ACCZ(acc) { acc[0] = (f32x4)0.0f; acc[1] = (f32x4)0.0f; }

// ---------------------------------------------------------------------------
// kmain v12: r11 structure at 2x TLP. 1 block per l, 1024 thr = 16 waves
// (4 wm x 4 wn; wave = 16 rows x 32 cols). LDS 96KB; 2-buffer B stream,
// load-before-use; 6 lgkmcnt-only barriers + 1 pre-fbuf.
// ---------------------------------------------------------------------------
__global__ __launch_bounds__(1024, 4) void kmain(
    const float* __restrict__ x,
    const float* __restrict__ b1, const float* __restrict__ b2,
    const float* __restrict__ b3, const float* __restrict__ b4,
    const unsigned short* __restrict__ ws, float* __restrict__ out) {

    __shared__ __align__(16) unsigned char smem[98304];
    unsigned short* h1  = (unsigned short*)smem;             // 64KB [64][512]
    unsigned short* xs  = (unsigned short*)(smem + 65536);   // 16KB [64][128]
    unsigned short* cmb = (unsigned short*)(smem + 81920);   // 16KB [64][128]
    float* l2m1 = (float*)(smem + 49152);      // [8][128] f32 in h1 tail
    float* l2m2 = (float*)(smem + 53248);
    int*   l2i  = (int*)  (smem + 57344);
    float* fm1  = (float*)(smem + 81920);      // [128] in cmb (dead pre-G2-epi)
    float* fm2  = fm1 + 128;
    int*   fi   = (int*)(fm2 + 128);
    float* fbuf = (float*)(smem + 65536);      // 32KB fp32 over xs+cmb (G4 epi)

    const int tid  = threadIdx.x;
    const int lane = tid & 63;
    const int wid  = tid >> 6;                 // 0..15
    const int wm   = wid >> 2;                 // 0..3 (16 rows)
    const int wn   = wid & 3;                  // 0..3 (32 cols)
    const int l    = blockIdx.x;
    const int lr   = lane & 15;
    const int lk   = (lane >> 4) << 3;
    const int lq   = (lane >> 4) << 2;
    const int row0 = wm * 16;
    const int rowa = row0 + lr;                // this lane's A row
    const float* xg = x + l * 64 * 128;
    const unsigned short* wsw = ws + wn * 4096 + lane * 8;

    // ---- prologue: chunk 0 in flight ----
    bf16x8 bq0[8], bq1[8];
    ldch8(wsw, 0, bq0);

    float bias1v[8], bias3v[8], bias2v[2], bias4v[2];
#pragma unroll
    for (int c = 0; c < 4; c++)
#pragma unroll
        for (int n = 0; n < 2; n++) {
            bias1v[c * 2 + n] = b1[c * 128 + wn * 32 + n * 16 + lr];
            bias3v[c * 2 + n] = b3[c * 128 + wn * 32 + n * 16 + lr];
        }
#pragma unroll
    for (int n = 0; n < 2; n++) {
        bias2v[n] = b2[wn * 32 + n * 16 + lr];
        bias4v[n] = b4[wn * 32 + n * 16 + lr];
    }

    // ---- P0: stage xs (vec, swizzled) + per-thread top-2 over 8 rows ----
    {
        int row  = tid >> 4;
        int col0 = (tid & 15) * 8;
        int base = row * 128 + col0;
        float4v v0 = *(const float4v*)(xg + base);
        float4v v1 = *(const float4v*)(xg + base + 4);
        unsigned short t8[8];
        float v[8] = {v0.x, v0.y, v0.z, v0.w, v1.x, v1.y, v1.z, v1.w};
#pragma unroll
        for (int e = 0; e < 8; e++) t8[e] = f2bfc(v[e]);
        u32x4 p;
        p.x = (unsigned)t8[0] | ((unsigned)t8[1] << 16);
        p.y = (unsigned)t8[2] | ((unsigned)t8[3] << 16);
        p.z = (unsigned)t8[4] | ((unsigned)t8[5] << 16);
        p.w = (unsigned)t8[6] | ((unsigned)t8[7] << 16);
        *(u32x4*)(&xs[SWZ(base, row)]) = p;

        int q = tid >> 7, d = tid & 127;       // q 0..7: 8 rows each
        float m1 = -3.4e38f, m2 = -3.4e38f; int i1 = -1;
#pragma unroll
        for (int i = 0; i < 8; i++) {
            int rr = q * 8 + i;
            float vv = xg[rr * 128 + d];
            if (vv > m1) { m2 = m1; m1 = vv; i1 = rr; }
            else if (vv > m2) { m2 = vv; }
        }
        l2m1[q * 128 + d] = m1; l2m2[q * 128 + d] = m2; l2i[q * 128 + d] = i1;
    }
    bar_lds();

    // ---- P1: merge 8 partials -> fm1/fm2/fi ----
    if (tid < 128) {
        int d = tid;
        float m1 = l2m1[d], m2 = l2m2[d]; int i1 = l2i[d];
#pragma unroll
        for (int h = 1; h < 8; h++) {
            float a1 = l2m1[h * 128 + d], a2 = l2m2[h * 128 + d]; int ai = l2i[h * 128 + d];
            if (a1 > m1) { m2 = fmaxf(m1, a2); m1 = a1; i1 = ai; }
            else         { m2 = fmaxf(m2, a1); }
        }
        fm1[d] = m1; fm2[d] = m2; fi[d] = i1;
    }
    bar_lds();

    // ---- build G1 A-fragments (wave's 16 rows) in registers ----
    bf16x8 a1f[4];
#pragma unroll
    for (int ks = 0; ks < 4; ks++) {
        int k0 = ks * 32 + lk;
        float4v v1a = *(const float4v*)(&fm1[k0]);
        float4v v1b = *(const float4v*)(&fm1[k0 + 4]);
        float4v v2a = *(const float4v*)(&fm2[k0]);
        float4v v2b = *(const float4v*)(&fm2[k0 + 4]);
        i32x4  ia  = *(const i32x4*)(&fi[k0]);
        i32x4  ib  = *(const i32x4*)(&fi[k0 + 4]);
        float v1[8] = {v1a.x, v1a.y, v1a.z, v1a.w, v1b.x, v1b.y, v1b.z, v1b.w};
        float v2[8] = {v2a.x, v2a.y, v2a.z, v2a.w, v2b.x, v2b.y, v2b.z, v2b.w};
        int   ii[8] = {ia.x, ia.y, ia.z, ia.w, ib.x, ib.y, ib.z, ib.w};
        unsigned short t8[8];
#pragma unroll
        for (int e = 0; e < 8; e++) {
            float s = (ii[e] == rowa) ? v2[e] : v1[e];
            t8[e] = f2bfc(fmaxf(s, 0.0f));
        }
        u32x4 p;
        p.x = (unsigned)t8[0] | ((unsigned)t8[1] << 16);
        p.y = (unsigned)t8[2] | ((unsigned)t8[3] << 16);
        p.z = (unsigned)t8[4] | ((unsigned)t8[5] << 16);
        p.w = (unsigned)t8[6] | ((unsigned)t8[7] << 16);
        a1f[ks] = __builtin_bit_cast(bf16x8, p);
    }

    f32x4 acc[2];
    float bc[2];

    // ---- G1: chunks 0..3 (A in regs); load c+1 before use of c ----
    ldch8(wsw, 1, bq1); ACCZ(acc); mmRegA(a1f, bq0, acc);
    bc[0] = bias1v[0]; bc[1] = bias1v[1];
    epi_store<true>(h1, 512, 0, acc, bc, lr, lq, row0, wn);
    ldch8(wsw, 2, bq0); ACCZ(acc); mmRegA(a1f, bq1, acc);
    bc[0] = bias1v[2]; bc[1] = bias1v[3];
    epi_store<true>(h1, 512, 128, acc, bc, lr, lq, row0, wn);
    ldch8(wsw, 3, bq1); ACCZ(acc); mmRegA(a1f, bq0, acc);
    bc[0] = bias1v[4]; bc[1] = bias1v[5];
    epi_store<true>(h1, 512, 256, acc, bc, lr, lq, row0, wn);
    ldch8(wsw, 4, bq0); ACCZ(acc); mmRegA(a1f, bq1, acc);
    bc[0] = bias1v[6]; bc[1] = bias1v[7];
    epi_store<true>(h1, 512, 384, acc, bc, lr, lq, row0, wn);
    bar_lds();

    // ---- G2: chunks 4..7 (A = h1 K-chunks, acc persists) ----
    ACCZ(acc);
    ldch8(wsw, 5, bq1); mmA_lds(h1, 512, 0,   bq0, rowa, lk, acc);
    ldch8(wsw, 6, bq0); mmA_lds(h1, 512, 128, bq1, rowa, lk, acc);
    ldch8(wsw, 7, bq1); mmA_lds(h1, 512, 256, bq0, rowa, lk, acc);
    ldch8(wsw, 8, bq0); mmA_lds(h1, 512, 384, bq1, rowa, lk, acc);
    epi_store<false>(cmb, 128, 0, acc, bias2v, lr, lq, row0, wn);
    bar_lds();

    // ---- G3: chunks 8..15 (nc 0..3 x {xs, cmb}) ----
    ACCZ(acc);
    ldch8(wsw, 9,  bq1); mmA_lds(xs,  128, 0, bq0, rowa, lk, acc);
    ldch8(wsw, 10, bq0); mmA_lds(cmb, 128, 0, bq1, rowa, lk, acc);
    bc[0] = bias3v[0]; bc[1] = bias3v[1];
    epi_store<true>(h1, 512, 0, acc, bc, lr, lq, row0, wn);
    ACCZ(acc);
    ldch8(wsw, 11, bq1); mmA_lds(xs,  128, 0, bq0, rowa, lk, acc);
    ldch8(wsw, 12, bq0); mmA_lds(cmb, 128, 0, bq1, rowa, lk, acc);
    bc[0] = bias3v[2]; bc[1] = bias3v[3];
    epi_store<true>(h1, 512, 128, acc, bc, lr, lq, row0, wn);
    ACCZ(acc);
    ldch8(wsw, 13, bq1); mmA_lds(xs,  128, 0, bq0, rowa, lk, acc);
    ldch8(wsw, 14, bq0); mmA_lds(cmb, 128, 0, bq1, rowa, lk, acc);
    bc[0] = bias3v[4]; bc[1] = bias3v[5];
    epi_store<true>(h1, 512, 256, acc, bc, lr, lq, row0, wn);
    ACCZ(acc);
    ldch8(wsw, 15, bq1); mmA_lds(xs,  128, 0, bq0, rowa, lk, acc);
    ldch8(wsw, 16, bq0); mmA_lds(cmb, 128, 0, bq1, rowa, lk, acc);
    bc[0] = bias3v[6]; bc[1] = bias3v[7];
    epi_store<true>(h1, 512, 384, acc, bc, lr, lq, row0, wn);
    bar_lds();

    // ---- G4: chunks 16..19 (A = h1) ----
    float4v xr[2];
#pragma unroll
    for (int it = 0; it < 2; it++) {
        int f = tid + it * 1024;
        xr[it] = *(const float4v*)(&xg[(f >> 5) * 128 + (f & 31) * 4]);
    }
    ACCZ(acc);
    ldch8(wsw, 17, bq1); mmA_lds(h1, 512, 0,   bq0, rowa, lk, acc);
    ldch8(wsw, 18, bq0); mmA_lds(h1, 512, 128, bq1, rowa, lk, acc);
    ldch8(wsw, 19, bq1); mmA_lds(h1, 512, 256, bq0, rowa, lk, acc);
    mmA_lds(h1, 512, 384, bq1, rowa, lk, acc);
    // fbuf overlays xs+cmb (dead after G3); h1 reads done per-wave above
    {
#pragma unroll
        for (int n = 0; n < 2; n++) {
            int col = wn * 32 + n * 16 + lr;
#pragma unroll
            for (int r = 0; r < 4; r++)
                fbuf[(row0 + lq + r) * 128 + col] = acc[n][r] + bias4v[n];
        }
    }
    bar_lds();

    // ---- coalesced residual + fp32 store ----
#pragma unroll
    for (int it = 0; it < 2; it++) {
        int f = tid + it * 1024;
        int row = f >> 5, c0 = (f & 31) * 4;
        float4v h = *(const float4v*)(&fbuf[row * 128 + c0]);
        float4v o;
        o.x = h.x + xr[it].x; o.y = h.y + xr[it].y;
        o.z = h.z + xr[it].z; o.w = h.w + xr[it].w;
        *(float4v*)(&out[(l * 64 + row) * 128 + c0]) = o;
    }
}

extern "C" void kernel_launch(void* const* d_in, const int* in_sizes, int n_in,
                              void* d_out, int out_size, void* d_ws, size_t ws_size,
                              hipStream_t stream) {
    const float* x  = (const float*)d_in[0];
    const float* W1 = (const float*)d_in[1];
    const float* b1 = (const float*)d_in[2];
    const float* W2 = (const float*)d_in[3];
    const float* b2 = (const float*)d_in[4];
    const float* W3 = (const float*)d_in[5];
    const float* b3 = (const float*)d_in[6];
    const float* W4 = (const float*)d_in[7];
    const float* b4 = (const float*)d_in[8];
    unsigned short* ws = (unsigned short*)d_ws;
    float* out = (float*)d_out;

    kprep<<<320, 256, 0, stream>>>(W1, W2, W3, W4, ws);
    kmain<<<256, 1024, 0, stream>>>(x, b1, b2, b3, b4, ws, out);
}

// Round 18
// 31.863 us; speedup vs baseline: 1.2536x; 1.2536x over previous
//
#include <hip/hip_runtime.h>

typedef __attribute__((ext_vector_type(8))) __bf16 bf16x8;
typedef __attribute__((ext_vector_type(4))) float f32x4;
typedef __attribute__((ext_vector_type(4))) float float4v;
typedef __attribute__((ext_vector_type(4))) unsigned int u32x4;
typedef __attribute__((ext_vector_type(4))) int i32x4;

__device__ __forceinline__ unsigned short f2bfc(float f) {
    __bf16 h = (__bf16)f;
    return __builtin_bit_cast(unsigned short, h);
}

// swizzle on ushort index: XOR bits 3..5 with (row&7)
#define SWZ(idx, row) ((idx) ^ (((row) & 7) << 3))

// barrier flushing LDS ops only; global loads stay in flight
__device__ __forceinline__ void bar_lds() {
    asm volatile("s_waitcnt lgkmcnt(0)" ::: "memory");
    __builtin_amdgcn_s_barrier();
    asm volatile("" ::: "memory");
}

// ---------------------------------------------------------------------------
// kprep v4 (verified): coalesced LDS-transpose -> chunk-major frag image.
// frag (1KB): lane l = col cb*16+(l&15), k ks*32+(l>>4)*8..+7 of W^T.
// chunk i = ws[i*16384 .. +16384) ushorts, i=0..19.
// ---------------------------------------------------------------------------
__global__ __launch_bounds__(256) void kprep(
    const float* __restrict__ W1, const float* __restrict__ W2,
    const float* __restrict__ W3, const float* __restrict__ W4,
    unsigned short* __restrict__ ws) {
    __shared__ unsigned short tile[32][33];
    int b = blockIdx.x, t = threadIdx.x;
    const float* W; int ld, tk, tn, wsel;
    if (b < 64)        { W = W1; ld = 512; tk = b >> 4;          tn = b & 15;         wsel = 0; }
    else if (b < 128)  { W = W2; ld = 128; tk = (b - 64) >> 2;   tn = (b - 64) & 3;   wsel = 1; }
    else if (b < 256)  { W = W3; ld = 512; tk = (b - 128) >> 4;  tn = (b - 128) & 15; wsel = 2; }
    else               { W = W4; ld = 128; tk = (b - 256) >> 2;  tn = (b - 256) & 3;  wsel = 3; }
#pragma unroll
    for (int it = 0; it < 4; it++) {
        int e = t + it * 256;
        int kr = e >> 5, nc = e & 31;
        tile[kr][nc] = f2bfc(W[(tk * 32 + kr) * ld + tn * 32 + nc]);
    }
    __syncthreads();
    int ks = tk;
#pragma unroll
    for (int it = 0; it < 2; it++) {
        int u2  = (t + it * 256) * 2;
        int cbl = u2 >> 9;
        int w   = u2 & 511;
        int lane = w >> 3, e0 = w & 7;
        int c  = lane & 15;
        int kk = (lane >> 4) * 8 + e0;
        unsigned int lo = tile[kk][cbl * 16 + c];
        unsigned int hi = tile[kk + 1][cbl * 16 + c];
        int cb = tn * 2 + cbl;
        int fi;
        if (wsel == 0)      fi = (cb >> 3) * 32 + (cb & 7) * 4 + ks;
        else if (wsel == 1) fi = 128 + (ks >> 2) * 32 + cb * 4 + (ks & 3);
        else if (wsel == 2) fi = 256 + ((cb >> 3) * 2 + (ks >> 2)) * 32 + (cb & 7) * 4 + (ks & 3);
        else                fi = 512 + (ks >> 2) * 32 + cb * 4 + (ks & 3);
        ((unsigned int*)ws)[fi * 256 + (w >> 1)] = lo | (hi << 16);
    }
}

// load one chunk's 8 frags for this wave; plain loads -- compiler schedules
__device__ __forceinline__ void ldch8(const unsigned short* __restrict__ wsw, int i,
                                      bf16x8 (&B)[8]) {
#pragma unroll
    for (int n = 0; n < 2; n++)
#pragma unroll
        for (int ks = 0; ks < 4; ks++)
            B[ks * 2 + n] = *(const bf16x8*)(wsw + i * 16384 + n * 2048 + ks * 512);
}

__device__ __forceinline__ void mmA_lds(const unsigned short* __restrict__ A,
                                        int astride, int akoff, const bf16x8 (&b)[8],
                                        int lr, int lk, int wm, f32x4 (&acc)[2][2]) {
#pragma unroll
    for (int ks = 0; ks < 4; ks++) {
        bf16x8 a[2];
#pragma unroll
        for (int m = 0; m < 2; m++) {
            int row = wm * 32 + m * 16 + lr;
            a[m] = *(const bf16x8*)(&A[SWZ(row * astride + akoff + ks * 32 + lk, row)]);
        }
#pragma unroll
        for (int m = 0; m < 2; m++)
#pragma unroll
            for (int n = 0; n < 2; n++)
                acc[m][n] = __builtin_amdgcn_mfma_f32_16x16x32_bf16(a[m], b[ks * 2 + n], acc[m][n], 0, 0, 0);
    }
}

__device__ __forceinline__ void mmRegA(const bf16x8 (&a1f)[2][4], const bf16x8 (&b)[8],
                                       f32x4 (&acc)[2][2]) {
#pragma unroll
    for (int ks = 0; ks < 4; ks++)
#pragma unroll
        for (int m = 0; m < 2; m++)
#pragma unroll
            for (int n = 0; n < 2; n++)
                acc[m][n] = __builtin_amdgcn_mfma_f32_16x16x32_bf16(a1f[m][ks], b[ks * 2 + n], acc[m][n], 0, 0, 0);
}

template<bool RELU>
__device__ __forceinline__ void epi_store(unsigned short* dst, int dstride, int colbase,
                                          const f32x4 (&acc)[2][2], const float (&bias)[2],
                                          int lr, int lq, int wm, int wn) {
#pragma unroll
    for (int n = 0; n < 2; n++) {
        int col = colbase + wn * 32 + n * 16 + lr;
#pragma unroll
        for (int m = 0; m < 2; m++)
#pragma unroll
            for (int r = 0; r < 4; r++) {
                int row = wm * 32 + m * 16 + lq + r;
                float v = acc[m][n][r] + bias[n];
                if (RELU) v = fmaxf(v, 0.0f);
                dst[SWZ(row * dstride + col, row)] = f2bfc(v);
            }
    }
}

#define ACCZ(acc) { _Pragma("unroll") for (int m = 0; m < 2; m++) { acc[m][0] = (f32x4)0.0f; acc[m][1] = (f32x4)0.0f; } }

// ---------------------------------------------------------------------------
// kmain (r11, best-measured 31.9us): 1 block per l, 512 thr (2m x 4n waves),
// LDS 96KB, 3-buffer compiler-scheduled B stream, 6 lgkmcnt-only barriers.
// ---------------------------------------------------------------------------
__global__ __launch_bounds__(512, 2) void kmain(
    const float* __restrict__ x,
    const float* __restrict__ b1, const float* __restrict__ b2,
    const float* __restrict__ b3, const float* __restrict__ b4,
    const unsigned short* __restrict__ ws, float* __restrict__ out) {

    __shared__ __align__(16) unsigned char smem[98304];
    unsigned short* h1  = (unsigned short*)smem;             // 64KB [64][512]
    unsigned short* xs  = (unsigned short*)(smem + 65536);   // 16KB [64][128]
    unsigned short* cmb = (unsigned short*)(smem + 81920);   // 16KB [64][128]
    float* l2m1 = (float*)(smem + 49152);      // [4][128] in h1 tail
    float* l2m2 = l2m1 + 512;
    int*   l2i  = (int*)(l2m2 + 512);
    float* fm1  = (float*)(smem + 81920);      // [128] in cmb (dead pre-G2-epi)
    float* fm2  = fm1 + 128;
    int*   fi   = (int*)(fm2 + 128);
    float* fbuf = (float*)(smem + 65536);      // 32KB fp32 over xs+cmb (G4 epi)

    const int tid  = threadIdx.x;
    const int lane = tid & 63;
    const int wid  = tid >> 6;
    const int wm   = wid >> 2;                 // 0..1 (32 rows)
    const int wn   = wid & 3;                  // 0..3 (32 cols)
    const int l    = blockIdx.x;
    const int lr   = lane & 15;
    const int lk   = (lane >> 4) << 3;
    const int lq   = (lane >> 4) << 2;
    const float* xg = x + l * 64 * 128;
    const unsigned short* wsw = ws + wn * 4096 + lane * 8;

    // ---- prologue: chunks 0,1 in flight ----
    bf16x8 bq0[8], bq1[8], bq2[8];
    ldch8(wsw, 0, bq0);
    ldch8(wsw, 1, bq1);

    float bias1v[8], bias3v[8], bias2v[2], bias4v[2];
#pragma unroll
    for (int c = 0; c < 4; c++)
#pragma unroll
        for (int n = 0; n < 2; n++) {
            bias1v[c * 2 + n] = b1[c * 128 + wn * 32 + n * 16 + lr];
            bias3v[c * 2 + n] = b3[c * 128 + wn * 32 + n * 16 + lr];
        }
#pragma unroll
    for (int n = 0; n < 2; n++) {
        bias2v[n] = b2[wn * 32 + n * 16 + lr];
        bias4v[n] = b4[wn * 32 + n * 16 + lr];
    }

    // ---- P0: stage xs (vec) + per-thread top-2 over 16 rows ----
    {
        int rp = tid >> 4, col0 = (tid & 15) * 8;
#pragma unroll
        for (int it = 0; it < 2; it++) {
            int row  = rp + it * 32;
            int base = row * 128 + col0;
            float4v v0 = *(const float4v*)(xg + base);
            float4v v1 = *(const float4v*)(xg + base + 4);
            unsigned short t8[8];
            float v[8] = {v0.x, v0.y, v0.z, v0.w, v1.x, v1.y, v1.z, v1.w};
#pragma unroll
            for (int e = 0; e < 8; e++) t8[e] = f2bfc(v[e]);
            u32x4 p;
            p.x = (unsigned)t8[0] | ((unsigned)t8[1] << 16);
            p.y = (unsigned)t8[2] | ((unsigned)t8[3] << 16);
            p.z = (unsigned)t8[4] | ((unsigned)t8[5] << 16);
            p.w = (unsigned)t8[6] | ((unsigned)t8[7] << 16);
            *(u32x4*)(&xs[SWZ(base, row)]) = p;
        }
        int q = tid >> 7, d = tid & 127;
        float m1 = -3.4e38f, m2 = -3.4e38f; int i1 = -1;
#pragma unroll
        for (int i = 0; i < 16; i++) {
            int row = q * 16 + i;
            float v = xg[row * 128 + d];
            if (v > m1) { m2 = m1; m1 = v; i1 = row; }
            else if (v > m2) { m2 = v; }
        }
        l2m1[q * 128 + d] = m1; l2m2[q * 128 + d] = m2; l2i[q * 128 + d] = i1;
    }
    bar_lds();

    // ---- P1: merge 4 partials -> fm1/fm2/fi ----
    if (tid < 128) {
        int d = tid;
        float m1 = l2m1[d], m2 = l2m2[d]; int i1 = l2i[d];
#pragma unroll
        for (int h = 1; h < 4; h++) {
            float a1 = l2m1[h * 128 + d], a2 = l2m2[h * 128 + d]; int ai = l2i[h * 128 + d];
            if (a1 > m1) { m2 = fmaxf(m1, a2); m1 = a1; i1 = ai; }
            else         { m2 = fmaxf(m2, a1); }
        }
        fm1[d] = m1; fm2[d] = m2; fi[d] = i1;
    }
    bar_lds();

    // ---- build G1 A-fragments in registers ----
    bf16x8 a1f[2][4];
#pragma unroll
    for (int ks = 0; ks < 4; ks++) {
        int k0 = ks * 32 + lk;
        float4v v1a = *(const float4v*)(&fm1[k0]);
        float4v v1b = *(const float4v*)(&fm1[k0 + 4]);
        float4v v2a = *(const float4v*)(&fm2[k0]);
        float4v v2b = *(const float4v*)(&fm2[k0 + 4]);
        i32x4  ia  = *(const i32x4*)(&fi[k0]);
        i32x4  ib  = *(const i32x4*)(&fi[k0 + 4]);
        float v1[8] = {v1a.x, v1a.y, v1a.z, v1a.w, v1b.x, v1b.y, v1b.z, v1b.w};
        float v2[8] = {v2a.x, v2a.y, v2a.z, v2a.w, v2b.x, v2b.y, v2b.z, v2b.w};
        int   ii[8] = {ia.x, ia.y, ia.z, ia.w, ib.x, ib.y, ib.z, ib.w};
#pragma unroll
        for (int m = 0; m < 2; m++) {
            int j = wm * 32 + m * 16 + lr;
            unsigned short t8[8];
#pragma unroll
            for (int e = 0; e < 8; e++) {
                float s = (ii[e] == j) ? v2[e] : v1[e];
                t8[e] = f2bfc(fmaxf(s, 0.0f));
            }
            u32x4 p;
            p.x = (unsigned)t8[0] | ((unsigned)t8[1] << 16);
            p.y = (unsigned)t8[2] | ((unsigned)t8[3] << 16);
            p.z = (unsigned)t8[4] | ((unsigned)t8[5] << 16);
            p.w = (unsigned)t8[6] | ((unsigned)t8[7] << 16);
            a1f[m][ks] = __builtin_bit_cast(bf16x8, p);
        }
    }

    f32x4 acc[2][2];
    float bc[2];

    // ---- G1: chunks 0..3 (A in regs) ----
    ACCZ(acc); ldch8(wsw, 2, bq2); mmRegA(a1f, bq0, acc);
    bc[0] = bias1v[0]; bc[1] = bias1v[1];
    epi_store<true>(h1, 512, 0, acc, bc, lr, lq, wm, wn);
    ACCZ(acc); ldch8(wsw, 3, bq0); mmRegA(a1f, bq1, acc);
    bc[0] = bias1v[2]; bc[1] = bias1v[3];
    epi_store<true>(h1, 512, 128, acc, bc, lr, lq, wm, wn);
    ACCZ(acc); ldch8(wsw, 4, bq1); mmRegA(a1f, bq2, acc);
    bc[0] = bias1v[4]; bc[1] = bias1v[5];
    epi_store<true>(h1, 512, 256, acc, bc, lr, lq, wm, wn);
    ACCZ(acc); ldch8(wsw, 5, bq2); mmRegA(a1f, bq0, acc);
    bc[0] = bias1v[6]; bc[1] = bias1v[7];
    epi_store<true>(h1, 512, 384, acc, bc, lr, lq, wm, wn);
    bar_lds();

    // ---- G2: chunks 4..7 (A = h1 K-chunks, acc persists) ----
    ACCZ(acc);
    ldch8(wsw, 6, bq0); mmA_lds(h1, 512, 0,   bq1, lr, lk, wm, acc);
    ldch8(wsw, 7, bq1); mmA_lds(h1, 512, 128, bq2, lr, lk, wm, acc);
    ldch8(wsw, 8, bq2); mmA_lds(h1, 512, 256, bq0, lr, lk, wm, acc);
    ldch8(wsw, 9, bq0); mmA_lds(h1, 512, 384, bq1, lr, lk, wm, acc);
    epi_store<false>(cmb, 128, 0, acc, bias2v, lr, lq, wm, wn);
    bar_lds();

    // ---- G3: chunks 8..15 (nc 0..3 x {xs, cmb}) ----
    ACCZ(acc);
    ldch8(wsw, 10, bq1); mmA_lds(xs,  128, 0, bq2, lr, lk, wm, acc);
    ldch8(wsw, 11, bq2); mmA_lds(cmb, 128, 0, bq0, lr, lk, wm, acc);
    bc[0] = bias3v[0]; bc[1] = bias3v[1];
    epi_store<true>(h1, 512, 0, acc, bc, lr, lq, wm, wn);
    ACCZ(acc);
    ldch8(wsw, 12, bq0); mmA_lds(xs,  128, 0, bq1, lr, lk, wm, acc);
    ldch8(wsw, 13, bq1); mmA_lds(cmb, 128, 0, bq2, lr, lk, wm, acc);
    bc[0] = bias3v[2]; bc[1] = bias3v[3];
    epi_store<true>(h1, 512, 128, acc, bc, lr, lq, wm, wn);
    ACCZ(acc);
    ldch8(wsw, 14, bq2); mmA_lds(xs,  128, 0, bq0, lr, lk, wm, acc);
    ldch8(wsw, 15, bq0); mmA_lds(cmb, 128, 0, bq1, lr, lk, wm, acc);
    bc[0] = bias3v[4]; bc[1] = bias3v[5];
    epi_store<true>(h1, 512, 256, acc, bc, lr, lq, wm, wn);
    ACCZ(acc);
    ldch8(wsw, 16, bq1); mmA_lds(xs,  128, 0, bq2, lr, lk, wm, acc);
    ldch8(wsw, 17, bq2); mmA_lds(cmb, 128, 0, bq0, lr, lk, wm, acc);
    bc[0] = bias3v[6]; bc[1] = bias3v[7];
    epi_store<true>(h1, 512, 384, acc, bc, lr, lq, wm, wn);
    bar_lds();

    // ---- G4: chunks 16..19 (A = h1) ----
    float4v xr[4];
#pragma unroll
    for (int it = 0; it < 4; it++) {
        int f = tid + it * 512;
        xr[it] = *(const float4v*)(&xg[(f >> 5) * 128 + (f & 31) * 4]);
    }
    ACCZ(acc);
    ldch8(wsw, 18, bq0); mmA_lds(h1, 512, 0,   bq1, lr, lk, wm, acc);
    ldch8(wsw, 19, bq1); mmA_lds(h1, 512, 128, bq2, lr, lk, wm, acc);
    mmA_lds(h1, 512, 256, bq0, lr, lk, wm, acc);
    mmA_lds(h1, 512, 384, bq1, lr, lk, wm, acc);
#pragma unroll
    for (int n = 0; n < 2; n++) {
        int col = wn * 32 + n * 16 + lr;
#pragma unroll
        for (int m = 0; m < 2; m++)
#pragma unroll
            for (int r = 0; r < 4; r++) {
                int row = wm * 32 + m * 16 + lq + r;
                fbuf[row * 128 + col] = acc[m][n][r] + bias4v[n];
            }
    }
    bar_lds();

    // ---- coalesced residual + fp32 store ----
#pragma unroll
    for (int it = 0; it < 4; it++) {
        int f = tid + it * 512;
        int row = f >> 5, c0 = (f & 31) * 4;
        float4v h = *(const float4v*)(&fbuf[row * 128 + c0]);
        float4v o;
        o.x = h.x + xr[it].x; o.y = h.y + xr[it].y;
        o.z = h.z + xr[it].z; o.w = h.w + xr[it].w;
        *(float4v*)(&out[(l * 64 + row) * 128 + c0]) = o;
    }
}

extern "C" void kernel_launch(void* const* d_in, const int* in_sizes, int n_in,
                              void* d_out, int out_size, void* d_ws, size_t ws_size,
                              hipStream_t stream) {
    const float* x  = (const float*)d_in[0];
    const float* W1 = (const float*)d_in[1];
    const float* b1 = (const float*)d_in[2];
    const float* W2 = (const float*)d_in[3];
    const float* b2 = (const float*)d_in[4];
    const float* W3 = (const float*)d_in[5];
    const float* b3 = (const float*)d_in[6];
    const float* W4 = (const float*)d_in[7];
    const float* b4 = (const float*)d_in[8];
    unsigned short* ws = (unsigned short*)d_ws;
    float* out = (float*)d_out;

    kprep<<<320, 256, 0, stream>>>(W1, W2, W3, W4, ws);
    kmain<<<256, 512, 0, stream>>>(x, b1, b2, b3, b4, ws, out);
}